// Round 7
// baseline (306.611 us; speedup 1.0000x reference)
//
#include <hip/hip_runtime.h>

typedef __attribute__((ext_vector_type(8))) short short8;
typedef __attribute__((ext_vector_type(4))) float f32x4;
typedef unsigned short u16;

#define T_SEQ 2048
#define C_DIM 2048
#define QKV_N 3072
#define HD 64
#define QSCALE 0.18033688011112042f   // (1/8) * log2(e): folds score scale + exp2 base

// ---- helpers -------------------------------------------------------------

static __device__ __forceinline__ u16 f2bf(float f) {
    unsigned u = __builtin_bit_cast(unsigned, f);
    unsigned rounding = 0x7fffu + ((u >> 16) & 1u);
    return (u16)((u + rounding) >> 16);
}

static __device__ __forceinline__ void gld_lds16(void* lds, const void* g) {
    __builtin_amdgcn_global_load_lds(
        (const __attribute__((address_space(1))) unsigned int*)g,
        (__attribute__((address_space(3))) unsigned int*)lds, 16, 0, 0);
}

// ---- merged f32->bf16 convert (x) + weight transpose+convert -------------

__global__ __launch_bounds__(256) void prep_all(const float* __restrict__ x,
                                                const float* __restrict__ Wq,
                                                const float* __restrict__ Wk,
                                                const float* __restrict__ Wv,
                                                const float* __restrict__ Wo,
                                                u16* __restrict__ xb,
                                                u16* __restrict__ Wt,
                                                u16* __restrict__ Wot) {
    __shared__ float tile[32][33];
    int bx = blockIdx.x;
    if (bx >= 160) {                       // convert part
        int id = (bx - 160) * 64 + blockIdx.y;
        int i = (id * 256 + threadIdx.x) * 4;
        f32x4 v = *(const f32x4*)(x + i);
        u16* o = xb + i;
        o[0] = f2bf(v[0]); o[1] = f2bf(v[1]); o[2] = f2bf(v[2]); o[3] = f2bf(v[3]);
        return;
    }
    const float* W; u16* D; int N, row_off;
    if (bx < 64)      { W = Wq; D = Wt;  N = 2048; row_off = 0;    }
    else if (bx < 80) { W = Wk; D = Wt;  N = 512;  row_off = 2048; bx -= 64; }
    else if (bx < 96) { W = Wv; D = Wt;  N = 512;  row_off = 2560; bx -= 80; }
    else              { W = Wo; D = Wot; N = 2048; row_off = 0;    bx -= 96; }
    int n0 = bx * 32, k0 = blockIdx.y * 32;
    int tx = threadIdx.x & 31, ty = threadIdx.x >> 5;  // ty 0..7
#pragma unroll
    for (int i = 0; i < 4; i++)
        tile[ty + i * 8][tx] = W[(size_t)(k0 + ty + i * 8) * N + n0 + tx];
    __syncthreads();
#pragma unroll
    for (int i = 0; i < 4; i++)
        D[(size_t)(row_off + n0 + ty + i * 8) * 2048 + k0 + tx] = f2bf(tile[tx][ty + i * 8]);
}

// ---- GEMM qkv + fused RoPE epilogue (BM=128, BN=64, BK=64, dbuf) ---------
// 48KB LDS -> 3 blocks/CU; grid (16,48) = 768 = 3.0/CU exact.

__global__ __launch_bounds__(256) void gemm_qkv(const u16* __restrict__ A,
                                                const u16* __restrict__ BT,
                                                const float* __restrict__ sn,
                                                const float* __restrict__ cs,
                                                u16* __restrict__ qb,
                                                u16* __restrict__ kb,
                                                u16* __restrict__ vb) {
    const int K = 2048;
    __shared__ alignas(16) u16 As[2][128][64];
    __shared__ alignas(16) u16 Bs[2][64][64];
    const int m0 = blockIdx.x * 128;
    const int bn0 = blockIdx.y * 64;
    const int w = threadIdx.x >> 6, lane = threadIdx.x & 63;
    const int lo = lane & 15, hi = lane >> 4;
    const int wr = w >> 1, wc = w & 1;
    const int srcsw = ((lane & 7) ^ (lane >> 3)) * 8;

    f32x4 zero4 = {0.f, 0.f, 0.f, 0.f};
    f32x4 acc[4][2];
#pragma unroll
    for (int m = 0; m < 4; m++)
#pragma unroll
        for (int n = 0; n < 2; n++) acc[m][n] = zero4;

    auto stage = [&](int buf, int k0) {
#pragma unroll
        for (int j = 0; j < 6; j++) {
            int s = j * 4 + w;
            if (s < 16) {
                int row = s * 8 + (lane >> 3);
                gld_lds16((char*)&As[buf][0][0] + s * 1024,
                          A + (size_t)(m0 + row) * K + k0 + srcsw);
            } else {
                int s2 = s - 16;
                int row = s2 * 8 + (lane >> 3);
                gld_lds16((char*)&Bs[buf][0][0] + s2 * 1024,
                          BT + (size_t)(bn0 + row) * K + k0 + srcsw);
            }
        }
    };

    stage(0, 0);
    __syncthreads();
    const int nk = K >> 6;
    for (int t = 0; t < nk; t++) {
        const int cur = t & 1;
        if (t + 1 < nk) stage(cur ^ 1, (t + 1) * 64);
#pragma unroll
        for (int kk = 0; kk < 2; kk++) {
            const int csw = ((kk * 4 + hi) ^ (lo & 7)) << 4;
            short8 a[4], b[2];
#pragma unroll
            for (int m = 0; m < 4; m++) {
                int r = wr * 64 + m * 16 + lo;
                a[m] = *(const short8*)((const char*)&As[cur][0][0] + r * 128 + csw);
            }
#pragma unroll
            for (int n = 0; n < 2; n++) {
                int r = wc * 32 + n * 16 + lo;
                b[n] = *(const short8*)((const char*)&Bs[cur][0][0] + r * 128 + csw);
            }
#pragma unroll
            for (int m = 0; m < 4; m++)
#pragma unroll
                for (int n = 0; n < 2; n++)
                    acc[m][n] = __builtin_amdgcn_mfma_f32_16x16x32_bf16(a[m], b[n], acc[m][n], 0, 0, 0);
        }
        __syncthreads();
    }
    // fused RoPE epilogue
    const bool odd = (lo & 1);
#pragma unroll
    for (int m = 0; m < 4; m++)
#pragma unroll
        for (int n = 0; n < 2; n++) {
            const int col = bn0 + wc * 32 + n * 16 + lo;
#pragma unroll
            for (int r = 0; r < 4; r++) {
                const int trow = m0 + wr * 64 + m * 16 + hi * 4 + r;
                float v = acc[m][n][r];
                float p = __shfl_xor(v, 1);
                if (col >= 2560) {                       // V: no rope
                    vb[(size_t)trow * 512 + (col - 2560)] = f2bf(v);
                } else {
                    const int pr = (col & 63) >> 1;
                    const float s = sn[trow * 32 + pr], c = cs[trow * 32 + pr];
                    float o = odd ? (p * s + v * c) : (v * c - p * s);
                    if (col < 2048) {                    // Q: prescale
                        qb[(size_t)trow * C_DIM + col] = f2bf(o * QSCALE);
                    } else {                             // K
                        const int cc = col - 2048;
                        kb[((size_t)(cc >> 6) * T_SEQ + trow) * 64 + (cc & 63)] = f2bf(o);
                    }
                }
            }
        }
}

// ---- GEMM v3 (pure): C[M][N] = A[M][K] * BT[N][K]^T ----------------------

template <int NF>
__global__ __launch_bounds__(256) void gemm_bt(const u16* __restrict__ A,
                                               const u16* __restrict__ BT,
                                               float* __restrict__ C,
                                               int M, int N, int K) {
    __shared__ alignas(16) u16 As[2][128][64];
    __shared__ alignas(16) u16 Bs[2][32 * NF][64];
    const int m0 = blockIdx.x * 128;
    const int bn0 = blockIdx.y * (32 * NF);
    const int w = threadIdx.x >> 6, lane = threadIdx.x & 63;
    const int lo = lane & 15, hi = lane >> 4;
    const int wr = w >> 1, wc = w & 1;
    const int srcsw = ((lane & 7) ^ (lane >> 3)) * 8;

    f32x4 zero4 = {0.f, 0.f, 0.f, 0.f};
    f32x4 acc[4][NF];
#pragma unroll
    for (int m = 0; m < 4; m++)
#pragma unroll
        for (int n = 0; n < NF; n++) acc[m][n] = zero4;

    const int NSEG = 16 + 4 * NF;
    auto stage = [&](int buf, int k0) {
#pragma unroll
        for (int j = 0; j < NSEG / 4; j++) {
            int s = j * 4 + w;
            if (s < 16) {
                int row = s * 8 + (lane >> 3);
                gld_lds16((char*)&As[buf][0][0] + s * 1024,
                          A + (size_t)(m0 + row) * K + k0 + srcsw);
            } else {
                int s2 = s - 16;
                int row = s2 * 8 + (lane >> 3);
                gld_lds16((char*)&Bs[buf][0][0] + s2 * 1024,
                          BT + (size_t)(bn0 + row) * K + k0 + srcsw);
            }
        }
    };

    stage(0, 0);
    __syncthreads();
    const int nk = K >> 6;
    for (int t = 0; t < nk; t++) {
        const int cur = t & 1;
        if (t + 1 < nk) stage(cur ^ 1, (t + 1) * 64);
#pragma unroll
        for (int kk = 0; kk < 2; kk++) {
            const int csw = ((kk * 4 + hi) ^ (lo & 7)) << 4;
            short8 a[4], b[NF];
#pragma unroll
            for (int m = 0; m < 4; m++) {
                int r = wr * 64 + m * 16 + lo;
                a[m] = *(const short8*)((const char*)&As[cur][0][0] + r * 128 + csw);
            }
#pragma unroll
            for (int n = 0; n < NF; n++) {
                int r = wc * 16 * NF + n * 16 + lo;
                b[n] = *(const short8*)((const char*)&Bs[cur][0][0] + r * 128 + csw);
            }
#pragma unroll
            for (int m = 0; m < 4; m++)
#pragma unroll
                for (int n = 0; n < NF; n++)
                    acc[m][n] = __builtin_amdgcn_mfma_f32_16x16x32_bf16(a[m], b[n], acc[m][n], 0, 0, 0);
        }
        __syncthreads();
    }
#pragma unroll
    for (int m = 0; m < 4; m++)
#pragma unroll
        for (int n = 0; n < NF; n++) {
            int col = bn0 + wc * 16 * NF + n * 16 + lo;
#pragma unroll
            for (int r = 0; r < 4; r++) {
                int row = m0 + wr * 64 + m * 16 + hi * 4 + r;
                C[(size_t)row * N + col] = acc[m][n][r];
            }
        }
}

// ---- V transpose: vb[t][512] (bf16) -> vt[kvh][d][t] ---------------------

__global__ __launch_bounds__(256) void vtrans(const u16* __restrict__ vb,
                                              u16* __restrict__ vt) {
    __shared__ unsigned tile[64][65];
    const int kvh = blockIdx.x >> 5, t0 = (blockIdx.x & 31) * 64;
    const int tx = threadIdx.x & 63, ty = threadIdx.x >> 6;   // ty 0..3
#pragma unroll
    for (int i = 0; i < 16; i++) {
        int r = ty * 16 + i;
        tile[r][tx] = vb[(size_t)(t0 + r) * 512 + kvh * 64 + tx];
    }
    __syncthreads();
#pragma unroll
    for (int i = 0; i < 16; i++) {
        int d = ty * 16 + i;
        vt[((size_t)kvh * 64 + d) * T_SEQ + t0 + tx] = (u16)tile[tx][d];
    }
}

// ---- flash attention v7: NO K/V staging (L2-resident), barrier-free ------
// grid (T/64, 32 heads), 256 threads, LDS = Ps only (8KB, wave-private).
// K fragments load straight from kb (coalesced 2KB/wave pattern); V^T
// fragments from vt (L2, 128x reuse). Waves fully independent: per-wave
// key range, no __syncthreads anywhere. P = exp2(S), Q pre-scaled.

__global__ __launch_bounds__(256) void attn_fwd(const u16* __restrict__ qb,
                                                const u16* __restrict__ kb,
                                                const u16* __restrict__ vt,
                                                u16* __restrict__ ob,
                                                const int* __restrict__ winp) {
    __shared__ alignas(16) u16 Ps[4][16][64];
    const int window = *winp;
    const int h = blockIdx.y, kvh = h >> 2;
    const int q0 = blockIdx.x * 64;
    const int w = threadIdx.x >> 6, lane = threadIdx.x & 63;
    const int lo = lane & 15, hi = lane >> 4;

    const int qlo_w = q0 + w * 16, qhi_w = qlo_w + 15;
    const int qrow = qlo_w + lo;
    const short8 qa0 = *(const short8*)(qb + (size_t)qrow * C_DIM + h * HD + hi * 8);
    const short8 qa1 = *(const short8*)(qb + (size_t)qrow * C_DIM + h * HD + 32 + hi * 8);

    const u16* kbase = kb + (size_t)kvh * T_SEQ * HD;
    const u16* vbase = vt + (size_t)kvh * HD * T_SEQ;

    f32x4 zero4 = {0.f, 0.f, 0.f, 0.f};
    f32x4 acc[4];
#pragma unroll
    for (int dt = 0; dt < 4; dt++) acc[dt] = zero4;
    float lreg[4] = {0.f, 0.f, 0.f, 0.f};

    int ktb = qlo_w - window; if (ktb < 0) ktb = 0; ktb &= ~63;

    for (int kt = ktb; kt <= qhi_w; kt += 64) {
        const bool interior = (kt + 63 <= qlo_w) && (qhi_w - kt <= window);
        f32x4 s0, s1, s2, s3;
        __builtin_amdgcn_s_setprio(1);
        {
#define QK_TILE(SD, NT)                                                              \
            {                                                                        \
                const u16* kp = kbase + (size_t)(kt + (NT) * 16 + lo) * HD + hi * 8; \
                const short8 kf0 = *(const short8*)(kp);                             \
                const short8 kf1 = *(const short8*)(kp + 32);                        \
                f32x4 z = zero4;                                                     \
                z = __builtin_amdgcn_mfma_f32_16x16x32_bf16(qa0, kf0, z, 0, 0, 0);   \
                z = __builtin_amdgcn_mfma_f32_16x16x32_bf16(qa1, kf1, z, 0, 0, 0);   \
                SD = z;                                                              \
            }
            QK_TILE(s0, 0) QK_TILE(s1, 1) QK_TILE(s2, 2) QK_TILE(s3, 3)
#undef QK_TILE
        }
        __builtin_amdgcn_s_setprio(0);
        if (!interior) {
#define MASK_TILE(SD, NT)                                                            \
            {                                                                        \
                int key = kt + (NT) * 16 + lo;                                       \
                _Pragma("unroll")                                                    \
                for (int r = 0; r < 4; r++) {                                        \
                    int q = qlo_w + hi * 4 + r;                                      \
                    if ((unsigned)(q - key) > (unsigned)window) SD[r] = -1e30f;      \
                }                                                                    \
            }
            MASK_TILE(s0, 0) MASK_TILE(s1, 1) MASK_TILE(s2, 2) MASK_TILE(s3, 3)
#undef MASK_TILE
        }
        // P = exp2(S), partial row-sums, P -> LDS (key-swizzled, wave-private)
#define EXP_TILE(SD, NT)                                                             \
        {                                                                            \
            _Pragma("unroll")                                                        \
            for (int r = 0; r < 4; r++) {                                            \
                float p = __builtin_amdgcn_exp2f(SD[r]);                             \
                lreg[r] += p;                                                        \
                int q16 = hi * 4 + r;                                                \
                Ps[w][q16][((NT) * 16 + lo) ^ ((q16 & 7) << 3)] = f2bf(p);           \
            }                                                                        \
        }
        EXP_TILE(s0, 0) EXP_TILE(s1, 1) EXP_TILE(s2, 2) EXP_TILE(s3, 3)
#undef EXP_TILE
        const short8 pa0 = *(const short8*)&Ps[w][lo][(hi ^ (lo & 7)) << 3];
        const short8 pa1 = *(const short8*)&Ps[w][lo][((4 + hi) ^ (lo & 7)) << 3];
        __builtin_amdgcn_s_setprio(1);
#pragma unroll
        for (int dt = 0; dt < 4; dt++) {
            const u16* vp = vbase + (size_t)(dt * 16 + lo) * T_SEQ + kt + hi * 8;
            const short8 vf0 = *(const short8*)(vp);
            const short8 vf1 = *(const short8*)(vp + 32);
            acc[dt] = __builtin_amdgcn_mfma_f32_16x16x32_bf16(pa0, vf0, acc[dt], 0, 0, 0);
            acc[dt] = __builtin_amdgcn_mfma_f32_16x16x32_bf16(pa1, vf1, acc[dt], 0, 0, 0);
        }
        __builtin_amdgcn_s_setprio(0);
    }
    float inv[4];
#pragma unroll
    for (int r = 0; r < 4; r++) {
        float l = lreg[r];
        l += __shfl_xor(l, 1);
        l += __shfl_xor(l, 2);
        l += __shfl_xor(l, 4);
        l += __shfl_xor(l, 8);
        inv[r] = 1.0f / l;
    }
#pragma unroll
    for (int dt = 0; dt < 4; dt++)
#pragma unroll
        for (int r = 0; r < 4; r++) {
            int q = qlo_w + hi * 4 + r;
            ob[(size_t)q * C_DIM + h * HD + dt * 16 + lo] = f2bf(acc[dt][r] * inv[r]);
        }
}

// ---- launcher ------------------------------------------------------------

extern "C" void kernel_launch(void* const* d_in, const int* in_sizes, int n_in,
                              void* d_out, int out_size, void* d_ws, size_t ws_size,
                              hipStream_t stream) {
    const float* x  = (const float*)d_in[0];
    const float* Wq = (const float*)d_in[1];
    const float* Wk = (const float*)d_in[2];
    const float* Wv = (const float*)d_in[3];
    const float* Wo = (const float*)d_in[4];
    const float* rs = (const float*)d_in[5];
    const float* rc = (const float*)d_in[6];
    const int*  win = (const int*)d_in[7];
    float* out = (float*)d_out;

    char* w = (char*)d_ws;
    u16*   xb   = (u16*)(w);                        //  8 MB  x bf16
    u16*   Wt   = (u16*)(w + (8ull  << 20));        // 12 MB  [Wq|Wk|Wv]^T bf16
    u16*   Wot  = (u16*)(w + (20ull << 20));        //  8 MB  Wo^T bf16
    u16*   qb   = (u16*)(w + (28ull << 20));        //  8 MB  rope'd q bf16
    u16*   kbuf = (u16*)(w + (36ull << 20));        //  2 MB  rope'd k [kvh][t][64]
    u16*   vb   = (u16*)(w + (38ull << 20));        //  2 MB  v bf16 [t][512]
    u16*   vtb  = (u16*)(w + (40ull << 20));        //  2 MB  v^T [kvh][d][t]
    u16*   attb = (u16*)(w + (42ull << 20));        //  8 MB  (ends at 50 MB)

    prep_all<<<dim3(224, 64), 256, 0, stream>>>(x, Wq, Wk, Wv, Wo, xb, Wt, Wot);
    gemm_qkv<<<dim3(16, 48), 256, 0, stream>>>(xb, Wt, rs, rc, qb, kbuf, vb);
    vtrans<<<256, 256, 0, stream>>>(vb, vtb);
    attn_fwd<<<dim3(32, 32), 256, 0, stream>>>(qb, kbuf, vtb, attb, win);
    gemm_bt<2><<<dim3(16, 32), 256, 0, stream>>>(attb, Wot, out, 2048, 2048, 2048);
}

// Round 9
// 225.716 us; speedup vs baseline: 1.3584x; 1.3584x over previous
//
#include <hip/hip_runtime.h>

typedef __attribute__((ext_vector_type(8))) short short8;
typedef __attribute__((ext_vector_type(4))) float f32x4;
typedef unsigned short u16;

#define T_SEQ 2048
#define C_DIM 2048
#define QKV_N 3072
#define HD 64
#define QSCALE 0.18033688011112042f   // (1/8) * log2(e): folds score scale + exp2 base

// ---- helpers -------------------------------------------------------------

static __device__ __forceinline__ u16 f2bf(float f) {
    unsigned u = __builtin_bit_cast(unsigned, f);
    unsigned rounding = 0x7fffu + ((u >> 16) & 1u);
    return (u16)((u + rounding) >> 16);
}

static __device__ __forceinline__ void gld_lds16(void* lds, const void* g) {
    __builtin_amdgcn_global_load_lds(
        (const __attribute__((address_space(1))) unsigned int*)g,
        (__attribute__((address_space(3))) unsigned int*)lds, 16, 0, 0);
}

// ---- merged f32->bf16 convert (x) + weight transpose+convert -------------

__global__ __launch_bounds__(256) void prep_all(const float* __restrict__ x,
                                                const float* __restrict__ Wq,
                                                const float* __restrict__ Wk,
                                                const float* __restrict__ Wv,
                                                const float* __restrict__ Wo,
                                                u16* __restrict__ xb,
                                                u16* __restrict__ Wt,
                                                u16* __restrict__ Wot) {
    __shared__ float tile[32][33];
    int bx = blockIdx.x;
    if (bx >= 160) {                       // convert part
        int id = (bx - 160) * 64 + blockIdx.y;
        int i = (id * 256 + threadIdx.x) * 4;
        f32x4 v = *(const f32x4*)(x + i);
        u16* o = xb + i;
        o[0] = f2bf(v[0]); o[1] = f2bf(v[1]); o[2] = f2bf(v[2]); o[3] = f2bf(v[3]);
        return;
    }
    const float* W; u16* D; int N, row_off;
    if (bx < 64)      { W = Wq; D = Wt;  N = 2048; row_off = 0;    }
    else if (bx < 80) { W = Wk; D = Wt;  N = 512;  row_off = 2048; bx -= 64; }
    else if (bx < 96) { W = Wv; D = Wt;  N = 512;  row_off = 2560; bx -= 80; }
    else              { W = Wo; D = Wot; N = 2048; row_off = 0;    bx -= 96; }
    int n0 = bx * 32, k0 = blockIdx.y * 32;
    int tx = threadIdx.x & 31, ty = threadIdx.x >> 5;  // ty 0..7
#pragma unroll
    for (int i = 0; i < 4; i++)
        tile[ty + i * 8][tx] = W[(size_t)(k0 + ty + i * 8) * N + n0 + tx];
    __syncthreads();
#pragma unroll
    for (int i = 0; i < 4; i++)
        D[(size_t)(row_off + n0 + ty + i * 8) * 2048 + k0 + tx] = f2bf(tile[tx][ty + i * 8]);
}

// ---- GEMM qkv + fused RoPE epilogue (BM=128, BN=64, BK=64, dbuf) ---------
// 48KB LDS -> 3 blocks/CU; grid (16,48) = 768 = 3.0/CU exact. XCD swizzle.

__global__ __launch_bounds__(256) void gemm_qkv(const u16* __restrict__ A,
                                                const u16* __restrict__ BT,
                                                const float* __restrict__ sn,
                                                const float* __restrict__ cs,
                                                u16* __restrict__ qb,
                                                u16* __restrict__ kb,
                                                u16* __restrict__ vb) {
    const int K = 2048;
    __shared__ alignas(16) u16 As[2][128][64];
    __shared__ alignas(16) u16 Bs[2][64][64];
    // XCD-aware swizzle: 768 blocks, 96/XCD chunk (bijective since 768%8==0)
    const int bid = blockIdx.y * 16 + blockIdx.x;
    const int swz = (bid & 7) * 96 + (bid >> 3);
    const int m0 = (swz & 15) * 128;
    const int bn0 = (swz >> 4) * 64;
    const int w = threadIdx.x >> 6, lane = threadIdx.x & 63;
    const int lo = lane & 15, hi = lane >> 4;
    const int wr = w >> 1, wc = w & 1;
    const int srcsw = ((lane & 7) ^ (lane >> 3)) * 8;

    f32x4 zero4 = {0.f, 0.f, 0.f, 0.f};
    f32x4 acc[4][2];
#pragma unroll
    for (int m = 0; m < 4; m++)
#pragma unroll
        for (int n = 0; n < 2; n++) acc[m][n] = zero4;

    auto stage = [&](int buf, int k0) {
#pragma unroll
        for (int j = 0; j < 6; j++) {
            int s = j * 4 + w;
            if (s < 16) {
                int row = s * 8 + (lane >> 3);
                gld_lds16((char*)&As[buf][0][0] + s * 1024,
                          A + (size_t)(m0 + row) * K + k0 + srcsw);
            } else {
                int s2 = s - 16;
                int row = s2 * 8 + (lane >> 3);
                gld_lds16((char*)&Bs[buf][0][0] + s2 * 1024,
                          BT + (size_t)(bn0 + row) * K + k0 + srcsw);
            }
        }
    };

    stage(0, 0);
    __syncthreads();
    const int nk = K >> 6;
    for (int t = 0; t < nk; t++) {
        const int cur = t & 1;
        if (t + 1 < nk) stage(cur ^ 1, (t + 1) * 64);
#pragma unroll
        for (int kk = 0; kk < 2; kk++) {
            const int csw = ((kk * 4 + hi) ^ (lo & 7)) << 4;
            short8 a[4], b[2];
#pragma unroll
            for (int m = 0; m < 4; m++) {
                int r = wr * 64 + m * 16 + lo;
                a[m] = *(const short8*)((const char*)&As[cur][0][0] + r * 128 + csw);
            }
#pragma unroll
            for (int n = 0; n < 2; n++) {
                int r = wc * 32 + n * 16 + lo;
                b[n] = *(const short8*)((const char*)&Bs[cur][0][0] + r * 128 + csw);
            }
#pragma unroll
            for (int m = 0; m < 4; m++)
#pragma unroll
                for (int n = 0; n < 2; n++)
                    acc[m][n] = __builtin_amdgcn_mfma_f32_16x16x32_bf16(a[m], b[n], acc[m][n], 0, 0, 0);
        }
        __syncthreads();
    }
    // fused RoPE epilogue
    const bool odd = (lo & 1);
#pragma unroll
    for (int m = 0; m < 4; m++)
#pragma unroll
        for (int n = 0; n < 2; n++) {
            const int col = bn0 + wc * 32 + n * 16 + lo;
#pragma unroll
            for (int r = 0; r < 4; r++) {
                const int trow = m0 + wr * 64 + m * 16 + hi * 4 + r;
                float v = acc[m][n][r];
                float p = __shfl_xor(v, 1);
                if (col >= 2560) {                       // V: no rope
                    vb[(size_t)trow * 512 + (col - 2560)] = f2bf(v);
                } else {
                    const int pr = (col & 63) >> 1;
                    const float s = sn[trow * 32 + pr], c = cs[trow * 32 + pr];
                    float o = odd ? (p * s + v * c) : (v * c - p * s);
                    if (col < 2048) {                    // Q: prescale
                        qb[(size_t)trow * C_DIM + col] = f2bf(o * QSCALE);
                    } else {                             // K
                        const int cc = col - 2048;
                        kb[((size_t)(cc >> 6) * T_SEQ + trow) * 64 + (cc & 63)] = f2bf(o);
                    }
                }
            }
        }
}

// ---- GEMM v3 (pure): C[M][N] = A[M][K] * BT[N][K]^T, XCD swizzle ---------

template <int NF>
__global__ __launch_bounds__(256) void gemm_bt(const u16* __restrict__ A,
                                               const u16* __restrict__ BT,
                                               float* __restrict__ C,
                                               int M, int N, int K) {
    __shared__ alignas(16) u16 As[2][128][64];
    __shared__ alignas(16) u16 Bs[2][32 * NF][64];
    const int nbx = gridDim.x, nwg = nbx * gridDim.y;
    const int bid = blockIdx.y * nbx + blockIdx.x;
    const int swz = (bid & 7) * (nwg >> 3) + (bid >> 3);   // nwg % 8 == 0
    const int m0 = (swz % nbx) * 128;
    const int bn0 = (swz / nbx) * (32 * NF);
    const int w = threadIdx.x >> 6, lane = threadIdx.x & 63;
    const int lo = lane & 15, hi = lane >> 4;
    const int wr = w >> 1, wc = w & 1;
    const int srcsw = ((lane & 7) ^ (lane >> 3)) * 8;

    f32x4 zero4 = {0.f, 0.f, 0.f, 0.f};
    f32x4 acc[4][NF];
#pragma unroll
    for (int m = 0; m < 4; m++)
#pragma unroll
        for (int n = 0; n < NF; n++) acc[m][n] = zero4;

    const int NSEG = 16 + 4 * NF;
    auto stage = [&](int buf, int k0) {
#pragma unroll
        for (int j = 0; j < NSEG / 4; j++) {
            int s = j * 4 + w;
            if (s < 16) {
                int row = s * 8 + (lane >> 3);
                gld_lds16((char*)&As[buf][0][0] + s * 1024,
                          A + (size_t)(m0 + row) * K + k0 + srcsw);
            } else {
                int s2 = s - 16;
                int row = s2 * 8 + (lane >> 3);
                gld_lds16((char*)&Bs[buf][0][0] + s2 * 1024,
                          BT + (size_t)(bn0 + row) * K + k0 + srcsw);
            }
        }
    };

    stage(0, 0);
    __syncthreads();
    const int nk = K >> 6;
    for (int t = 0; t < nk; t++) {
        const int cur = t & 1;
        if (t + 1 < nk) stage(cur ^ 1, (t + 1) * 64);
#pragma unroll
        for (int kk = 0; kk < 2; kk++) {
            const int csw = ((kk * 4 + hi) ^ (lo & 7)) << 4;
            short8 a[4], b[NF];
#pragma unroll
            for (int m = 0; m < 4; m++) {
                int r = wr * 64 + m * 16 + lo;
                a[m] = *(const short8*)((const char*)&As[cur][0][0] + r * 128 + csw);
            }
#pragma unroll
            for (int n = 0; n < NF; n++) {
                int r = wc * 16 * NF + n * 16 + lo;
                b[n] = *(const short8*)((const char*)&Bs[cur][0][0] + r * 128 + csw);
            }
#pragma unroll
            for (int m = 0; m < 4; m++)
#pragma unroll
                for (int n = 0; n < NF; n++)
                    acc[m][n] = __builtin_amdgcn_mfma_f32_16x16x32_bf16(a[m], b[n], acc[m][n], 0, 0, 0);
        }
        __syncthreads();
    }
#pragma unroll
    for (int m = 0; m < 4; m++)
#pragma unroll
        for (int n = 0; n < NF; n++) {
            int col = bn0 + wc * 16 * NF + n * 16 + lo;
#pragma unroll
            for (int r = 0; r < 4; r++) {
                int row = m0 + wr * 64 + m * 16 + hi * 4 + r;
                C[(size_t)row * N + col] = acc[m][n][r];
            }
        }
}

// ---- V transpose: vb[t][512] (bf16) -> vt[kvh][d][t] ---------------------

__global__ __launch_bounds__(256) void vtrans(const u16* __restrict__ vb,
                                              u16* __restrict__ vt) {
    __shared__ unsigned tile[64][65];
    const int kvh = blockIdx.x >> 5, t0 = (blockIdx.x & 31) * 64;
    const int tx = threadIdx.x & 63, ty = threadIdx.x >> 6;   // ty 0..3
#pragma unroll
    for (int i = 0; i < 16; i++) {
        int r = ty * 16 + i;
        tile[r][tx] = vb[(size_t)(t0 + r) * 512 + kvh * 64 + tx];
    }
    __syncthreads();
#pragma unroll
    for (int i = 0; i < 16; i++) {
        int d = ty * 16 + i;
        vt[((size_t)kvh * 64 + d) * T_SEQ + t0 + tx] = (u16)tile[tx][d];
    }
}

// ---- flash attention v8: staged dbuf (R6 structure) + XCD swizzle --------
// grid (T/64, 32 heads) remapped so each XCD's L2 serves 4 heads (2MB KV).
// 40960B LDS -> 4 blocks/CU. P = exp2(S) (Q pre-scaled by log2e/8).
// Fixed-max softmax; KVBLK=64 dbuf; XOR-swizzled staging; key-swizzled Ps.

__global__ __launch_bounds__(256) void attn_fwd(const u16* __restrict__ qb,
                                                const u16* __restrict__ kb,
                                                const u16* __restrict__ vt,
                                                u16* __restrict__ ob,
                                                const int* __restrict__ winp) {
    __shared__ alignas(16) char KsB[2][8192];
    __shared__ alignas(16) char VsB[2][8192];
    __shared__ alignas(16) u16 Ps[4][16][64];
    const int window = *winp;
    // XCD swizzle: 1024 blocks, 128/XCD chunk -> 4 heads per XCD L2
    const int bid = blockIdx.y * 32 + blockIdx.x;
    const int swz = (bid & 7) * 128 + (bid >> 3);
    const int h = swz >> 5, kvh = h >> 2;
    const int q0 = (swz & 31) * 64;
    const int w = threadIdx.x >> 6, lane = threadIdx.x & 63;
    const int lo = lane & 15, hi = lane >> 4;

    const int qrow = q0 + w * 16 + lo;
    const short8 qa0 = *(const short8*)(qb + (size_t)qrow * C_DIM + h * HD + hi * 8);
    const short8 qa1 = *(const short8*)(qb + (size_t)qrow * C_DIM + h * HD + 32 + hi * 8);

    f32x4 zero4 = {0.f, 0.f, 0.f, 0.f};
    f32x4 acc[4];
#pragma unroll
    for (int dt = 0; dt < 4; dt++) acc[dt] = zero4;
    float lreg[4] = {0.f, 0.f, 0.f, 0.f};

    int kt0 = q0 - window; if (kt0 < 0) kt0 = 0; kt0 &= ~63;
    const int qlo_w = q0 + w * 16, qhi_w = qlo_w + 15;
    const int nt = (q0 + 64 - kt0) >> 6;

    auto stage = [&](int buf, int kt) {
#pragma unroll
        for (int j = 0; j < 2; j++) {
            int c = (w * 2 + j) * 64 + lane;       // 16B chunk id 0..511
            int rr = c >> 3, sc = (c & 7) ^ (rr & 7);
            gld_lds16(KsB[buf] + (w * 2 + j) * 1024,
                      kb + ((size_t)kvh * T_SEQ + kt + rr) * 64 + sc * 8);
            gld_lds16(VsB[buf] + (w * 2 + j) * 1024,
                      vt + ((size_t)kvh * 64 + rr) * T_SEQ + kt + sc * 8);
        }
    };

    stage(0, kt0);
    __syncthreads();
    for (int i = 0; i < nt; i++) {
        const int kt = kt0 + i * 64;
        const int cur = i & 1;
        if (i + 1 < nt) stage(cur ^ 1, kt + 64);
        if (kt <= qhi_w && kt + 63 >= qlo_w - window) {
            const bool interior = (kt + 63 <= qlo_w) && (qhi_w - kt <= window);
            f32x4 s0, s1, s2, s3;
            __builtin_amdgcn_s_setprio(1);
            {
#define QK_TILE(SD, NT)                                                              \
                {                                                                    \
                    int key = (NT) * 16 + lo;                                        \
                    const short8 kf0 = *(const short8*)(KsB[cur] + key * 128 + ((hi ^ (key & 7)) << 4));       \
                    const short8 kf1 = *(const short8*)(KsB[cur] + key * 128 + (((4 + hi) ^ (key & 7)) << 4)); \
                    f32x4 z = zero4;                                                 \
                    z = __builtin_amdgcn_mfma_f32_16x16x32_bf16(qa0, kf0, z, 0, 0, 0);\
                    z = __builtin_amdgcn_mfma_f32_16x16x32_bf16(qa1, kf1, z, 0, 0, 0);\
                    SD = z;                                                          \
                }
                QK_TILE(s0, 0) QK_TILE(s1, 1) QK_TILE(s2, 2) QK_TILE(s3, 3)
#undef QK_TILE
            }
            __builtin_amdgcn_s_setprio(0);
            if (!interior) {
#define MASK_TILE(SD, NT)                                                            \
                {                                                                    \
                    int key = kt + (NT) * 16 + lo;                                   \
                    _Pragma("unroll")                                                \
                    for (int r = 0; r < 4; r++) {                                    \
                        int q = qlo_w + hi * 4 + r;                                  \
                        if ((unsigned)(q - key) > (unsigned)window) SD[r] = -1e30f;  \
                    }                                                                \
                }
                MASK_TILE(s0, 0) MASK_TILE(s1, 1) MASK_TILE(s2, 2) MASK_TILE(s3, 3)
#undef MASK_TILE
            }
            // P = exp2(S), partial row-sums, P -> LDS (key-swizzled)
#define EXP_TILE(SD, NT)                                                             \
            {                                                                        \
                _Pragma("unroll")                                                    \
                for (int r = 0; r < 4; r++) {                                        \
                    float p = __builtin_amdgcn_exp2f(SD[r]);                         \
                    lreg[r] += p;                                                    \
                    int q16 = hi * 4 + r;                                            \
                    Ps[w][q16][((NT) * 16 + lo) ^ ((q16 & 7) << 3)] = f2bf(p);       \
                }                                                                    \
            }
            EXP_TILE(s0, 0) EXP_TILE(s1, 1) EXP_TILE(s2, 2) EXP_TILE(s3, 3)
#undef EXP_TILE
            const short8 pa0 = *(const short8*)&Ps[w][lo][(hi ^ (lo & 7)) << 3];
            const short8 pa1 = *(const short8*)&Ps[w][lo][((4 + hi) ^ (lo & 7)) << 3];
            __builtin_amdgcn_s_setprio(1);
#pragma unroll
            for (int dt = 0; dt < 4; dt++) {
                int d = dt * 16 + lo;
                const short8 vf0 = *(const short8*)(VsB[cur] + d * 128 + ((hi ^ (d & 7)) << 4));
                const short8 vf1 = *(const short8*)(VsB[cur] + d * 128 + (((4 + hi) ^ (d & 7)) << 4));
                acc[dt] = __builtin_amdgcn_mfma_f32_16x16x32_bf16(pa0, vf0, acc[dt], 0, 0, 0);
                acc[dt] = __builtin_amdgcn_mfma_f32_16x16x32_bf16(pa1, vf1, acc[dt], 0, 0, 0);
            }
            __builtin_amdgcn_s_setprio(0);
        }
        __syncthreads();
    }
    float inv[4];
#pragma unroll
    for (int r = 0; r < 4; r++) {
        float l = lreg[r];
        l += __shfl_xor(l, 1);
        l += __shfl_xor(l, 2);
        l += __shfl_xor(l, 4);
        l += __shfl_xor(l, 8);
        inv[r] = 1.0f / l;
    }
#pragma unroll
    for (int dt = 0; dt < 4; dt++)
#pragma unroll
        for (int r = 0; r < 4; r++) {
            int q = qlo_w + hi * 4 + r;
            ob[(size_t)q * C_DIM + h * HD + dt * 16 + lo] = f2bf(acc[dt][r] * inv[r]);
        }
}

// ---- launcher ------------------------------------------------------------

extern "C" void kernel_launch(void* const* d_in, const int* in_sizes, int n_in,
                              void* d_out, int out_size, void* d_ws, size_t ws_size,
                              hipStream_t stream) {
    const float* x  = (const float*)d_in[0];
    const float* Wq = (const float*)d_in[1];
    const float* Wk = (const float*)d_in[2];
    const float* Wv = (const float*)d_in[3];
    const float* Wo = (const float*)d_in[4];
    const float* rs = (const float*)d_in[5];
    const float* rc = (const float*)d_in[6];
    const int*  win = (const int*)d_in[7];
    float* out = (float*)d_out;

    char* w = (char*)d_ws;
    u16*   xb   = (u16*)(w);                        //  8 MB  x bf16
    u16*   Wt   = (u16*)(w + (8ull  << 20));        // 12 MB  [Wq|Wk|Wv]^T bf16
    u16*   Wot  = (u16*)(w + (20ull << 20));        //  8 MB  Wo^T bf16
    u16*   qb   = (u16*)(w + (28ull << 20));        //  8 MB  rope'd q bf16
    u16*   kbuf = (u16*)(w + (36ull << 20));        //  2 MB  rope'd k [kvh][t][64]
    u16*   vb   = (u16*)(w + (38ull << 20));        //  2 MB  v bf16 [t][512]
    u16*   vtb  = (u16*)(w + (40ull << 20));        //  2 MB  v^T [kvh][d][t]
    u16*   attb = (u16*)(w + (42ull << 20));        //  8 MB  (ends at 50 MB)

    prep_all<<<dim3(224, 64), 256, 0, stream>>>(x, Wq, Wk, Wv, Wo, xb, Wt, Wot);
    gemm_qkv<<<dim3(16, 48), 256, 0, stream>>>(xb, Wt, rs, rc, qb, kbuf, vb);
    vtrans<<<256, 256, 0, stream>>>(vb, vtb);
    attn_fwd<<<dim3(32, 32), 256, 0, stream>>>(qb, kbuf, vtb, attb, win);
    gemm_bt<2><<<dim3(16, 32), 256, 0, stream>>>(attb, Wot, out, 2048, 2048, 2048);
}